// Round 1
// baseline (1446.265 us; speedup 1.0000x reference)
//
#include <hip/hip_runtime.h>
#include <hip/hip_bf16.h>

#define EPS 1e-5f

// ---------------------------------------------------------------------------
// LayerNorm over last dim = 256. One wave (64 threads) per row; float4 loads.
// ---------------------------------------------------------------------------
__global__ __launch_bounds__(64) void ln256_kernel(
    const float* __restrict__ in, float* __restrict__ out,
    const float* __restrict__ g, const float* __restrict__ b) {
  int row = blockIdx.x;
  int lane = threadIdx.x;  // 0..63
  const float4* inr = reinterpret_cast<const float4*>(in + (size_t)row * 256);
  float4 x = inr[lane];
  float s = x.x + x.y + x.z + x.w;
  float sq = x.x * x.x + x.y * x.y + x.z * x.z + x.w * x.w;
#pragma unroll
  for (int off = 32; off >= 1; off >>= 1) {
    s += __shfl_xor(s, off);
    sq += __shfl_xor(sq, off);
  }
  float mean = s * (1.0f / 256.0f);
  float var = sq * (1.0f / 256.0f) - mean * mean;
  float inv = rsqrtf(var + EPS);
  float4 gv = reinterpret_cast<const float4*>(g)[lane];
  float4 bv = reinterpret_cast<const float4*>(b)[lane];
  float4 o;
  o.x = (x.x - mean) * inv * gv.x + bv.x;
  o.y = (x.y - mean) * inv * gv.y + bv.y;
  o.z = (x.z - mean) * inv * gv.z + bv.z;
  o.w = (x.w - mean) * inv * gv.w + bv.w;
  reinterpret_cast<float4*>(out + (size_t)row * 256)[lane] = o;
}

// ---------------------------------------------------------------------------
// Fused pair LayerNorm (over 128) + bias einsum:
//   bT[h][k][q] = sum_d LN(pair[q,k,:])[d] * bw[h][d]
// One wave per (q,k) position.
// ---------------------------------------------------------------------------
__global__ __launch_bounds__(64) void pair_bias_kernel(
    const float* __restrict__ pair, const float* __restrict__ g,
    const float* __restrict__ b, const float* __restrict__ bw,
    float* __restrict__ bT) {
  int idx = blockIdx.x;  // q*256 + k
  int q = idx >> 8;
  int k = idx & 255;
  int lane = threadIdx.x;
  float2 z = reinterpret_cast<const float2*>(pair + (size_t)idx * 128)[lane];
  float s = z.x + z.y;
  float sq = z.x * z.x + z.y * z.y;
#pragma unroll
  for (int off = 32; off >= 1; off >>= 1) {
    s += __shfl_xor(s, off);
    sq += __shfl_xor(sq, off);
  }
  float mean = s * (1.0f / 128.0f);
  float inv = rsqrtf(sq * (1.0f / 128.0f) - mean * mean + EPS);
  float2 gv = reinterpret_cast<const float2*>(g)[lane];
  float2 bv = reinterpret_cast<const float2*>(b)[lane];
  float z0 = (z.x - mean) * inv * gv.x + bv.x;
  float z1 = (z.y - mean) * inv * gv.y + bv.y;
#pragma unroll
  for (int h = 0; h < 8; ++h) {
    float2 w = reinterpret_cast<const float2*>(bw + h * 128)[lane];
    float p = z0 * w.x + z1 * w.y;
#pragma unroll
    for (int off = 32; off >= 1; off >>= 1) p += __shfl_xor(p, off);
    if (lane == 0) bT[((size_t)h * 256 + k) * 256 + q] = p;
  }
}

// ---------------------------------------------------------------------------
// GEMM: out[M,N] = A[M,K] @ W[N,K]^T  (+ bias + epilogue)
// EPI 0: out = acc + bias
// EPI 1: out = out * sigmoid(acc + bias)          (gate; in-place on out)
// EPI 2: out = res + acc + bias                   (residual)
// EPI 3: out = relu(acc + bias)
// Tiles: BM=BN=64, BK=16, 256 threads, 4x4 microtile.
// ---------------------------------------------------------------------------
template <int EPI>
__global__ __launch_bounds__(256) void gemm_kernel(
    const float* __restrict__ A, const float* __restrict__ W,
    const float* __restrict__ bias, const float* res, float* out, int M, int N,
    int K) {
  __shared__ float As[16][68];
  __shared__ float Ws[16][68];
  int bm = blockIdx.x, bn = blockIdx.y;
  int t = threadIdx.x;
  int tx = t & 15, ty = t >> 4;
  int lrow = t >> 2;          // 0..63
  int lk4 = (t & 3) * 4;      // 0,4,8,12
  float acc[4][4] = {};
  const float* Aptr = A + (size_t)(bm * 64 + lrow) * K + lk4;
  const float* Wptr = W + (size_t)(bn * 64 + lrow) * K + lk4;
  for (int k0 = 0; k0 < K; k0 += 16) {
    float4 av = *reinterpret_cast<const float4*>(Aptr + k0);
    float4 wv = *reinterpret_cast<const float4*>(Wptr + k0);
    __syncthreads();  // previous compute done before overwrite
    As[lk4 + 0][lrow] = av.x;
    As[lk4 + 1][lrow] = av.y;
    As[lk4 + 2][lrow] = av.z;
    As[lk4 + 3][lrow] = av.w;
    Ws[lk4 + 0][lrow] = wv.x;
    Ws[lk4 + 1][lrow] = wv.y;
    Ws[lk4 + 2][lrow] = wv.z;
    Ws[lk4 + 3][lrow] = wv.w;
    __syncthreads();
#pragma unroll
    for (int kk = 0; kk < 16; ++kk) {
      float4 a4 = *reinterpret_cast<const float4*>(&As[kk][ty * 4]);
      float4 b4 = *reinterpret_cast<const float4*>(&Ws[kk][tx * 4]);
      float av2[4] = {a4.x, a4.y, a4.z, a4.w};
      float bv2[4] = {b4.x, b4.y, b4.z, b4.w};
#pragma unroll
      for (int i = 0; i < 4; ++i)
#pragma unroll
        for (int j = 0; j < 4; ++j) acc[i][j] += av2[i] * bv2[j];
    }
  }
  int m0 = bm * 64 + ty * 4;
  int n0 = bn * 64 + tx * 4;
  float4 bv = bias ? *reinterpret_cast<const float4*>(bias + n0)
                   : make_float4(0.f, 0.f, 0.f, 0.f);
#pragma unroll
  for (int i = 0; i < 4; ++i) {
    size_t off = (size_t)(m0 + i) * N + n0;
    float v[4];
#pragma unroll
    for (int j = 0; j < 4; ++j) v[j] = acc[i][j];
    v[0] += bv.x; v[1] += bv.y; v[2] += bv.z; v[3] += bv.w;
    if (EPI == 1) {
      float4 ov = *reinterpret_cast<const float4*>(out + off);
      float o4[4] = {ov.x, ov.y, ov.z, ov.w};
#pragma unroll
      for (int j = 0; j < 4; ++j) v[j] = o4[j] * (1.0f / (1.0f + __expf(-v[j])));
    } else if (EPI == 2) {
      float4 rv = *reinterpret_cast<const float4*>(res + off);
      v[0] += rv.x; v[1] += rv.y; v[2] += rv.z; v[3] += rv.w;
    } else if (EPI == 3) {
#pragma unroll
      for (int j = 0; j < 4; ++j) v[j] = fmaxf(v[j], 0.0f);
    }
    float4 vo = make_float4(v[0], v[1], v[2], v[3]);
    *reinterpret_cast<float4*>(out + off) = vo;
  }
}

// ---------------------------------------------------------------------------
// Row attention: block = (s,h), 256 threads = 256 query rows, 256 keys.
// qkv rows are s*256 + r, layout [q(256) | k(256) | v(256)], head h at h*32.
// bias bT[h][k][q] added to logits. Online softmax per thread.
// ---------------------------------------------------------------------------
__global__ __launch_bounds__(256) void attn_row_kernel(
    const float* __restrict__ qkv, const float* __restrict__ bT,
    float* __restrict__ o) {
  __shared__ float kt[256][36];
  __shared__ float vt[256][36];
  int blk = blockIdx.x;
  int s = blk >> 3;
  int h = blk & 7;
  int t = threadIdx.x;
  const float* base = qkv + (size_t)(s * 256 + t) * 768 + h * 32;
  const float scale = 0.17677669529663687f;  // 32^-0.5
  float q[32];
#pragma unroll
  for (int c4 = 0; c4 < 8; ++c4) {
    float4 k4 = *reinterpret_cast<const float4*>(base + 256 + c4 * 4);
    float4 v4 = *reinterpret_cast<const float4*>(base + 512 + c4 * 4);
    *reinterpret_cast<float4*>(&kt[t][c4 * 4]) = k4;
    *reinterpret_cast<float4*>(&vt[t][c4 * 4]) = v4;
    float4 q4 = *reinterpret_cast<const float4*>(base + c4 * 4);
    q[c4 * 4 + 0] = q4.x * scale;
    q[c4 * 4 + 1] = q4.y * scale;
    q[c4 * 4 + 2] = q4.z * scale;
    q[c4 * 4 + 3] = q4.w * scale;
  }
  __syncthreads();
  float m = -1e30f, l = 0.0f;
  float acc[32] = {};
  const float* brow = bT + (size_t)h * 65536 + t;  // bT[h][k][q=t]
  for (int k = 0; k < 256; ++k) {
    float sv = brow[(size_t)k * 256];
#pragma unroll
    for (int c = 0; c < 32; ++c) sv += q[c] * kt[k][c];
    float mnew = fmaxf(m, sv);
    float corr = __expf(m - mnew);
    float e = __expf(sv - mnew);
    l = l * corr + e;
#pragma unroll
    for (int c = 0; c < 32; ++c) acc[c] = acc[c] * corr + e * vt[k][c];
    m = mnew;
  }
  float rl = 1.0f / l;
  float* orow = o + (size_t)(s * 256 + t) * 256 + h * 32;
#pragma unroll
  for (int c4 = 0; c4 < 8; ++c4) {
    float4 vo = make_float4(acc[c4 * 4 + 0] * rl, acc[c4 * 4 + 1] * rl,
                            acc[c4 * 4 + 2] * rl, acc[c4 * 4 + 3] * rl);
    *reinterpret_cast<float4*>(orow + c4 * 4) = vo;
  }
}

// ---------------------------------------------------------------------------
// Column attention: block = (r,h), 128 threads = 128 query rows (s), 128 keys.
// Query row s lives at qkv row s*256 + r. No bias.
// ---------------------------------------------------------------------------
__global__ __launch_bounds__(128) void attn_col_kernel(
    const float* __restrict__ qkv, float* __restrict__ o) {
  __shared__ float kt[128][36];
  __shared__ float vt[128][36];
  int blk = blockIdx.x;
  int r = blk >> 3;
  int h = blk & 7;
  int t = threadIdx.x;  // s index
  const float* base = qkv + (size_t)(t * 256 + r) * 768 + h * 32;
  const float scale = 0.17677669529663687f;
  float q[32];
#pragma unroll
  for (int c4 = 0; c4 < 8; ++c4) {
    float4 k4 = *reinterpret_cast<const float4*>(base + 256 + c4 * 4);
    float4 v4 = *reinterpret_cast<const float4*>(base + 512 + c4 * 4);
    *reinterpret_cast<float4*>(&kt[t][c4 * 4]) = k4;
    *reinterpret_cast<float4*>(&vt[t][c4 * 4]) = v4;
    float4 q4 = *reinterpret_cast<const float4*>(base + c4 * 4);
    q[c4 * 4 + 0] = q4.x * scale;
    q[c4 * 4 + 1] = q4.y * scale;
    q[c4 * 4 + 2] = q4.z * scale;
    q[c4 * 4 + 3] = q4.w * scale;
  }
  __syncthreads();
  float m = -1e30f, l = 0.0f;
  float acc[32] = {};
  for (int k = 0; k < 128; ++k) {
    float sv = 0.0f;
#pragma unroll
    for (int c = 0; c < 32; ++c) sv += q[c] * kt[k][c];
    float mnew = fmaxf(m, sv);
    float corr = __expf(m - mnew);
    float e = __expf(sv - mnew);
    l = l * corr + e;
#pragma unroll
    for (int c = 0; c < 32; ++c) acc[c] = acc[c] * corr + e * vt[k][c];
    m = mnew;
  }
  float rl = 1.0f / l;
  float* orow = o + (size_t)(t * 256 + r) * 256 + h * 32;
#pragma unroll
  for (int c4 = 0; c4 < 8; ++c4) {
    float4 vo = make_float4(acc[c4 * 4 + 0] * rl, acc[c4 * 4 + 1] * rl,
                            acc[c4 * 4 + 2] * rl, acc[c4 * 4 + 3] * rl);
    *reinterpret_cast<float4*>(orow + c4 * 4) = vo;
  }
}

// ---------------------------------------------------------------------------
extern "C" void kernel_launch(void* const* d_in, const int* in_sizes, int n_in,
                              void* d_out, int out_size, void* d_ws,
                              size_t ws_size, hipStream_t stream) {
  (void)in_sizes; (void)n_in; (void)out_size; (void)ws_size;
  const float* node      = (const float*)d_in[0];
  const float* pair      = (const float*)d_in[1];
  const float* ln_mr_g   = (const float*)d_in[2];
  const float* ln_mr_b   = (const float*)d_in[3];
  const float* ln_z_g    = (const float*)d_in[4];
  const float* ln_z_b    = (const float*)d_in[5];
  const float* b_weights = (const float*)d_in[6];
  const float* row_qkv_w = (const float*)d_in[7];
  const float* row_qkv_b = (const float*)d_in[8];
  const float* row_gate_w= (const float*)d_in[9];
  const float* row_gate_b= (const float*)d_in[10];
  const float* row_o_w   = (const float*)d_in[11];
  const float* out_bias  = (const float*)d_in[12];
  const float* ln_mc_g   = (const float*)d_in[13];
  const float* ln_mc_b   = (const float*)d_in[14];
  const float* col_qkv_w = (const float*)d_in[15];
  const float* col_qkv_b = (const float*)d_in[16];
  const float* col_gate_w= (const float*)d_in[17];
  const float* col_gate_b= (const float*)d_in[18];
  const float* col_o_w   = (const float*)d_in[19];
  const float* col_o_b   = (const float*)d_in[20];
  const float* ln_t_g    = (const float*)d_in[21];
  const float* ln_t_b    = (const float*)d_in[22];
  const float* t_w1      = (const float*)d_in[23];
  const float* t_b1      = (const float*)d_in[24];
  const float* t_w2      = (const float*)d_in[25];
  const float* t_b2      = (const float*)d_in[26];
  float* out = (float*)d_out;

  const size_t NR = 32768;  // S*R rows
  float* ws = (float*)d_ws;
  float* buf_ln   = ws;                      // [32768,256]
  float* buf_o    = buf_ln + NR * 256;       // [32768,256]
  float* buf_node = buf_o + NR * 256;        // [32768,256]
  float* buf_bias = buf_node + NR * 256;     // [8,256,256] as [h][k][q]
  float* buf_qkv  = buf_bias + 8 * 256 * 256;// [32768,1024] max

  // ---- Phase A: MSARowAttentionWithPairBias ----
  ln256_kernel<<<32768, 64, 0, stream>>>(node, buf_ln, ln_mr_g, ln_mr_b);
  pair_bias_kernel<<<65536, 64, 0, stream>>>(pair, ln_z_g, ln_z_b, b_weights,
                                             buf_bias);
  gemm_kernel<0><<<dim3(512, 12), 256, 0, stream>>>(
      buf_ln, row_qkv_w, row_qkv_b, nullptr, buf_qkv, 32768, 768, 256);
  attn_row_kernel<<<1024, 256, 0, stream>>>(buf_qkv, buf_bias, buf_o);
  gemm_kernel<1><<<dim3(512, 4), 256, 0, stream>>>(
      buf_ln, row_gate_w, row_gate_b, nullptr, buf_o, 32768, 256, 256);
  gemm_kernel<2><<<dim3(512, 4), 256, 0, stream>>>(
      buf_o, row_o_w, out_bias, node, buf_node, 32768, 256, 256);

  // ---- Phase B: MSAColumnAttention ----
  ln256_kernel<<<32768, 64, 0, stream>>>(buf_node, buf_ln, ln_mc_g, ln_mc_b);
  gemm_kernel<0><<<dim3(512, 12), 256, 0, stream>>>(
      buf_ln, col_qkv_w, col_qkv_b, nullptr, buf_qkv, 32768, 768, 256);
  attn_col_kernel<<<2048, 128, 0, stream>>>(buf_qkv, buf_o);
  gemm_kernel<1><<<dim3(512, 4), 256, 0, stream>>>(
      buf_ln, col_gate_w, col_gate_b, nullptr, buf_o, 32768, 256, 256);
  gemm_kernel<2><<<dim3(512, 4), 256, 0, stream>>>(
      buf_o, col_o_w, col_o_b, buf_node, buf_node, 32768, 256, 256);

  // ---- Phase C: MSATransition ----
  ln256_kernel<<<32768, 64, 0, stream>>>(buf_node, buf_ln, ln_t_g, ln_t_b);
  gemm_kernel<3><<<dim3(512, 16), 256, 0, stream>>>(
      buf_ln, t_w1, t_b1, nullptr, buf_qkv, 32768, 1024, 256);
  gemm_kernel<2><<<dim3(512, 4), 256, 0, stream>>>(
      buf_qkv, t_w2, t_b2, buf_node, out, 32768, 256, 1024);
}

// Round 2
// 756.680 us; speedup vs baseline: 1.9113x; 1.9113x over previous
//
#include <hip/hip_runtime.h>
#include <hip/hip_bf16.h>

#define EPS 1e-5f

typedef __hip_bfloat16 bf16;
typedef __attribute__((ext_vector_type(8))) short short8v;   // 8 bf16 = 4 VGPRs
typedef __attribute__((ext_vector_type(4))) float f32x4;

// ---------------------------------------------------------------------------
// global -> LDS direct copy, 16B per lane
// ---------------------------------------------------------------------------
__device__ inline void load_lds16(const void* g, void* l) {
  __builtin_amdgcn_global_load_lds(
      (const __attribute__((address_space(1))) void*)g,
      (__attribute__((address_space(3))) void*)l, 16, 0, 0);
}

// ---------------------------------------------------------------------------
// f32 -> bf16 elementwise (weights), 4 elems/thread
// ---------------------------------------------------------------------------
__global__ __launch_bounds__(256) void cvt_bf16_kernel(
    const float* __restrict__ in, bf16* __restrict__ out, int n4) {
  int i = blockIdx.x * 256 + threadIdx.x;
  if (i >= n4) return;
  float4 v = reinterpret_cast<const float4*>(in)[i];
  union { ushort4 u; bf16 h[4]; } cv;
  cv.h[0] = __float2bfloat16(v.x);
  cv.h[1] = __float2bfloat16(v.y);
  cv.h[2] = __float2bfloat16(v.z);
  cv.h[3] = __float2bfloat16(v.w);
  reinterpret_cast<ushort4*>(out)[i] = cv.u;
}

// ---------------------------------------------------------------------------
// LayerNorm over last dim = 256 -> bf16 output. One wave per row.
// ---------------------------------------------------------------------------
__global__ __launch_bounds__(64) void ln256_bf_kernel(
    const float* __restrict__ in, bf16* __restrict__ out,
    const float* __restrict__ g, const float* __restrict__ b) {
  int row = blockIdx.x;
  int lane = threadIdx.x;
  float4 x = reinterpret_cast<const float4*>(in + (size_t)row * 256)[lane];
  float s = x.x + x.y + x.z + x.w;
  float sq = x.x * x.x + x.y * x.y + x.z * x.z + x.w * x.w;
#pragma unroll
  for (int off = 32; off >= 1; off >>= 1) {
    s += __shfl_xor(s, off);
    sq += __shfl_xor(sq, off);
  }
  float mean = s * (1.0f / 256.0f);
  float inv = rsqrtf(sq * (1.0f / 256.0f) - mean * mean + EPS);
  float4 gv = reinterpret_cast<const float4*>(g)[lane];
  float4 bv = reinterpret_cast<const float4*>(b)[lane];
  union { ushort4 u; bf16 h[4]; } cv;
  cv.h[0] = __float2bfloat16((x.x - mean) * inv * gv.x + bv.x);
  cv.h[1] = __float2bfloat16((x.y - mean) * inv * gv.y + bv.y);
  cv.h[2] = __float2bfloat16((x.z - mean) * inv * gv.z + bv.z);
  cv.h[3] = __float2bfloat16((x.w - mean) * inv * gv.w + bv.w);
  reinterpret_cast<ushort4*>(out + (size_t)row * 256)[lane] = cv.u;
}

// ---------------------------------------------------------------------------
// Fused pair LayerNorm + bias einsum: bT[h][k][q] (fp32, unchanged)
// ---------------------------------------------------------------------------
__global__ __launch_bounds__(64) void pair_bias_kernel(
    const float* __restrict__ pair, const float* __restrict__ g,
    const float* __restrict__ b, const float* __restrict__ bw,
    float* __restrict__ bT) {
  int idx = blockIdx.x;  // q*256 + k
  int q = idx >> 8;
  int k = idx & 255;
  int lane = threadIdx.x;
  float2 z = reinterpret_cast<const float2*>(pair + (size_t)idx * 128)[lane];
  float s = z.x + z.y;
  float sq = z.x * z.x + z.y * z.y;
#pragma unroll
  for (int off = 32; off >= 1; off >>= 1) {
    s += __shfl_xor(s, off);
    sq += __shfl_xor(sq, off);
  }
  float mean = s * (1.0f / 128.0f);
  float inv = rsqrtf(sq * (1.0f / 128.0f) - mean * mean + EPS);
  float2 gv = reinterpret_cast<const float2*>(g)[lane];
  float2 bv = reinterpret_cast<const float2*>(b)[lane];
  float z0 = (z.x - mean) * inv * gv.x + bv.x;
  float z1 = (z.y - mean) * inv * gv.y + bv.y;
#pragma unroll
  for (int h = 0; h < 8; ++h) {
    float2 w = reinterpret_cast<const float2*>(bw + h * 128)[lane];
    float p = z0 * w.x + z1 * w.y;
#pragma unroll
    for (int off = 32; off >= 1; off >>= 1) p += __shfl_xor(p, off);
    if (lane == 0) bT[((size_t)h * 256 + k) * 256 + q] = p;
  }
}

// ---------------------------------------------------------------------------
// MFMA GEMM: out[M,N] = A[M,K] @ W[N,K]^T (+bias +epilogue), bf16 in, fp32 acc
// m97 structure: 128x128 tile, BK=32, 4 waves (2x2), 4x4 16x16x32 frags/wave.
// EPI 0: fp32 out = acc + bias                     (qkv)
// EPI 1: bf16 out = aux * sigmoid(acc + bias)      (gate; aux = attn out f32)
// EPI 2: fp32 out = aux + acc + bias               (residual; aux = res f32)
// EPI 3: bf16 out = relu(acc + bias)               (transition hidden)
// ---------------------------------------------------------------------------
template <int EPI>
__global__ __launch_bounds__(256) void gemm_mfma_kernel(
    const bf16* __restrict__ A, const bf16* __restrict__ W,
    const float* __restrict__ bias, const float* __restrict__ aux, void* out,
    int N, int K) {
  __shared__ __align__(16) short As[128 * 32];
  __shared__ __align__(16) short Bs[128 * 32];
  int bm = blockIdx.x, bn = blockIdx.y;
  int tid = threadIdx.x;
  int w = tid >> 6, lane = tid & 63;
  int wr = w >> 1, wc = w & 1;  // wave tile 64x64
  int c0 = w * 64 + lane;       // staging chunk (16B each)
  int srow = c0 >> 2, skq = c0 & 3;
  const short* Abase = (const short*)(A + (size_t)(bm * 128) * K);
  const short* Wbase = (const short*)(W + (size_t)(bn * 128) * K);
  f32x4 acc[4][4] = {};
  int lrow = lane & 15, kq = lane >> 4;

  for (int k0 = 0; k0 < K; k0 += 32) {
    __syncthreads();  // LDS consumed by previous iter
    // stage A tile [128][32] and B tile [128][32], 16B/lane x2 each
    load_lds16(Abase + (size_t)srow * K + k0 + skq * 8, &As[c0 * 8]);
    load_lds16(Abase + (size_t)(srow + 64) * K + k0 + skq * 8,
               &As[(256 + c0) * 8]);
    load_lds16(Wbase + (size_t)srow * K + k0 + skq * 8, &Bs[c0 * 8]);
    load_lds16(Wbase + (size_t)(srow + 64) * K + k0 + skq * 8,
               &Bs[(256 + c0) * 8]);
    __syncthreads();  // drains vmcnt
    short8v af[4], bfv[4];
#pragma unroll
    for (int i = 0; i < 4; ++i)
      af[i] = *reinterpret_cast<const short8v*>(
          &As[(wr * 64 + i * 16 + lrow) * 32 + kq * 8]);
#pragma unroll
    for (int j = 0; j < 4; ++j)
      bfv[j] = *reinterpret_cast<const short8v*>(
          &Bs[(wc * 64 + j * 16 + lrow) * 32 + kq * 8]);
#pragma unroll
    for (int i = 0; i < 4; ++i)
#pragma unroll
      for (int j = 0; j < 4; ++j)
        acc[i][j] = __builtin_amdgcn_mfma_f32_16x16x32_bf16(af[i], bfv[j],
                                                            acc[i][j], 0, 0, 0);
  }

  // epilogue: C/D map col=lane&15, row=(lane>>4)*4+reg
  float* outF = (float*)out;
  bf16* outB = (bf16*)out;
  int r4 = (lane >> 4) * 4;
#pragma unroll
  for (int j = 0; j < 4; ++j) {
    int c = bn * 128 + wc * 64 + j * 16 + lrow;
    float bv = bias ? bias[c] : 0.0f;
#pragma unroll
    for (int i = 0; i < 4; ++i) {
      int r0 = bm * 128 + wr * 64 + i * 16 + r4;
#pragma unroll
      for (int reg = 0; reg < 4; ++reg) {
        size_t off = (size_t)(r0 + reg) * N + c;
        float v = acc[i][j][reg] + bv;
        if (EPI == 0) {
          outF[off] = v;
        } else if (EPI == 1) {
          float gt = 1.0f / (1.0f + __expf(-v));
          outB[off] = __float2bfloat16(aux[off] * gt);
        } else if (EPI == 2) {
          outF[off] = v + aux[off];
        } else {
          outB[off] = __float2bfloat16(fmaxf(v, 0.0f));
        }
      }
    }
  }
}

// ---------------------------------------------------------------------------
// Row attention (fp32, unchanged): block=(s,h), 256 threads = 256 query rows.
// ---------------------------------------------------------------------------
__global__ __launch_bounds__(256) void attn_row_kernel(
    const float* __restrict__ qkv, const float* __restrict__ bT,
    float* __restrict__ o) {
  __shared__ float kt[256][36];
  __shared__ float vt[256][36];
  int blk = blockIdx.x;
  int s = blk >> 3;
  int h = blk & 7;
  int t = threadIdx.x;
  const float* base = qkv + (size_t)(s * 256 + t) * 768 + h * 32;
  const float scale = 0.17677669529663687f;
  float q[32];
#pragma unroll
  for (int c4 = 0; c4 < 8; ++c4) {
    float4 k4 = *reinterpret_cast<const float4*>(base + 256 + c4 * 4);
    float4 v4 = *reinterpret_cast<const float4*>(base + 512 + c4 * 4);
    *reinterpret_cast<float4*>(&kt[t][c4 * 4]) = k4;
    *reinterpret_cast<float4*>(&vt[t][c4 * 4]) = v4;
    float4 q4 = *reinterpret_cast<const float4*>(base + c4 * 4);
    q[c4 * 4 + 0] = q4.x * scale;
    q[c4 * 4 + 1] = q4.y * scale;
    q[c4 * 4 + 2] = q4.z * scale;
    q[c4 * 4 + 3] = q4.w * scale;
  }
  __syncthreads();
  float m = -1e30f, l = 0.0f;
  float acc[32] = {};
  const float* brow = bT + (size_t)h * 65536 + t;
  for (int k = 0; k < 256; ++k) {
    float sv = brow[(size_t)k * 256];
#pragma unroll
    for (int c = 0; c < 32; ++c) sv += q[c] * kt[k][c];
    float mnew = fmaxf(m, sv);
    float corr = __expf(m - mnew);
    float e = __expf(sv - mnew);
    l = l * corr + e;
#pragma unroll
    for (int c = 0; c < 32; ++c) acc[c] = acc[c] * corr + e * vt[k][c];
    m = mnew;
  }
  float rl = 1.0f / l;
  float* orow = o + (size_t)(s * 256 + t) * 256 + h * 32;
#pragma unroll
  for (int c4 = 0; c4 < 8; ++c4) {
    float4 vo = make_float4(acc[c4 * 4 + 0] * rl, acc[c4 * 4 + 1] * rl,
                            acc[c4 * 4 + 2] * rl, acc[c4 * 4 + 3] * rl);
    *reinterpret_cast<float4*>(orow + c4 * 4) = vo;
  }
}

// ---------------------------------------------------------------------------
// Column attention (fp32, unchanged): block=(r,h), 128 threads = 128 s-rows.
// ---------------------------------------------------------------------------
__global__ __launch_bounds__(128) void attn_col_kernel(
    const float* __restrict__ qkv, float* __restrict__ o) {
  __shared__ float kt[128][36];
  __shared__ float vt[128][36];
  int blk = blockIdx.x;
  int r = blk >> 3;
  int h = blk & 7;
  int t = threadIdx.x;
  const float* base = qkv + (size_t)(t * 256 + r) * 768 + h * 32;
  const float scale = 0.17677669529663687f;
  float q[32];
#pragma unroll
  for (int c4 = 0; c4 < 8; ++c4) {
    float4 k4 = *reinterpret_cast<const float4*>(base + 256 + c4 * 4);
    float4 v4 = *reinterpret_cast<const float4*>(base + 512 + c4 * 4);
    *reinterpret_cast<float4*>(&kt[t][c4 * 4]) = k4;
    *reinterpret_cast<float4*>(&vt[t][c4 * 4]) = v4;
    float4 q4 = *reinterpret_cast<const float4*>(base + c4 * 4);
    q[c4 * 4 + 0] = q4.x * scale;
    q[c4 * 4 + 1] = q4.y * scale;
    q[c4 * 4 + 2] = q4.z * scale;
    q[c4 * 4 + 3] = q4.w * scale;
  }
  __syncthreads();
  float m = -1e30f, l = 0.0f;
  float acc[32] = {};
  for (int k = 0; k < 128; ++k) {
    float sv = 0.0f;
#pragma unroll
    for (int c = 0; c < 32; ++c) sv += q[c] * kt[k][c];
    float mnew = fmaxf(m, sv);
    float corr = __expf(m - mnew);
    float e = __expf(sv - mnew);
    l = l * corr + e;
#pragma unroll
    for (int c = 0; c < 32; ++c) acc[c] = acc[c] * corr + e * vt[k][c];
    m = mnew;
  }
  float rl = 1.0f / l;
  float* orow = o + (size_t)(t * 256 + r) * 256 + h * 32;
#pragma unroll
  for (int c4 = 0; c4 < 8; ++c4) {
    float4 vo = make_float4(acc[c4 * 4 + 0] * rl, acc[c4 * 4 + 1] * rl,
                            acc[c4 * 4 + 2] * rl, acc[c4 * 4 + 3] * rl);
    *reinterpret_cast<float4*>(orow + c4 * 4) = vo;
  }
}

// ---------------------------------------------------------------------------
extern "C" void kernel_launch(void* const* d_in, const int* in_sizes, int n_in,
                              void* d_out, int out_size, void* d_ws,
                              size_t ws_size, hipStream_t stream) {
  (void)in_sizes; (void)n_in; (void)out_size; (void)ws_size;
  const float* node      = (const float*)d_in[0];
  const float* pair      = (const float*)d_in[1];
  const float* ln_mr_g   = (const float*)d_in[2];
  const float* ln_mr_b   = (const float*)d_in[3];
  const float* ln_z_g    = (const float*)d_in[4];
  const float* ln_z_b    = (const float*)d_in[5];
  const float* b_weights = (const float*)d_in[6];
  const float* row_qkv_w = (const float*)d_in[7];
  const float* row_qkv_b = (const float*)d_in[8];
  const float* row_gate_w= (const float*)d_in[9];
  const float* row_gate_b= (const float*)d_in[10];
  const float* row_o_w   = (const float*)d_in[11];
  const float* out_bias  = (const float*)d_in[12];
  const float* ln_mc_g   = (const float*)d_in[13];
  const float* ln_mc_b   = (const float*)d_in[14];
  const float* col_qkv_w = (const float*)d_in[15];
  const float* col_qkv_b = (const float*)d_in[16];
  const float* col_gate_w= (const float*)d_in[17];
  const float* col_gate_b= (const float*)d_in[18];
  const float* col_o_w   = (const float*)d_in[19];
  const float* col_o_b   = (const float*)d_in[20];
  const float* ln_t_g    = (const float*)d_in[21];
  const float* ln_t_b    = (const float*)d_in[22];
  const float* t_w1      = (const float*)d_in[23];
  const float* t_b1      = (const float*)d_in[24];
  const float* t_w2      = (const float*)d_in[25];
  const float* t_b2      = (const float*)d_in[26];
  float* out = (float*)d_out;

  const size_t NR = 32768;
  char* p = (char*)d_ws;
  float* buf_node = (float*)p; p += NR * 256 * 4;
  float* buf_qkv  = (float*)p; p += NR * 768 * 4;   // reused as h_bf in phase C
  float* buf_o    = (float*)p; p += NR * 256 * 4;
  float* buf_bias = (float*)p; p += 8 * 256 * 256 * 4;
  bf16* ln_bf     = (bf16*)p;  p += NR * 256 * 2;
  bf16* g_bf      = (bf16*)p;  p += NR * 256 * 2;
  bf16* h_bf      = (bf16*)buf_qkv;  // phase C only; 67MB < 100MB region
  bf16* w_rqkv = (bf16*)p; p += 768 * 256 * 2;
  bf16* w_rg   = (bf16*)p; p += 256 * 256 * 2;
  bf16* w_ro   = (bf16*)p; p += 256 * 256 * 2;
  bf16* w_cqkv = (bf16*)p; p += 768 * 256 * 2;
  bf16* w_cg   = (bf16*)p; p += 256 * 256 * 2;
  bf16* w_co   = (bf16*)p; p += 256 * 256 * 2;
  bf16* w_t1   = (bf16*)p; p += 1024 * 256 * 2;
  bf16* w_t2   = (bf16*)p; p += 256 * 1024 * 2;

  // ---- weight conversions (fp32 -> bf16) ----
  cvt_bf16_kernel<<<192, 256, 0, stream>>>(row_qkv_w, w_rqkv, 49152);
  cvt_bf16_kernel<<<64, 256, 0, stream>>>(row_gate_w, w_rg, 16384);
  cvt_bf16_kernel<<<64, 256, 0, stream>>>(row_o_w, w_ro, 16384);
  cvt_bf16_kernel<<<192, 256, 0, stream>>>(col_qkv_w, w_cqkv, 49152);
  cvt_bf16_kernel<<<64, 256, 0, stream>>>(col_gate_w, w_cg, 16384);
  cvt_bf16_kernel<<<64, 256, 0, stream>>>(col_o_w, w_co, 16384);
  cvt_bf16_kernel<<<256, 256, 0, stream>>>(t_w1, w_t1, 65536);
  cvt_bf16_kernel<<<256, 256, 0, stream>>>(t_w2, w_t2, 65536);

  // ---- Phase A: MSARowAttentionWithPairBias ----
  ln256_bf_kernel<<<32768, 64, 0, stream>>>(node, ln_bf, ln_mr_g, ln_mr_b);
  pair_bias_kernel<<<65536, 64, 0, stream>>>(pair, ln_z_g, ln_z_b, b_weights,
                                             buf_bias);
  gemm_mfma_kernel<0><<<dim3(256, 6), 256, 0, stream>>>(
      ln_bf, w_rqkv, row_qkv_b, nullptr, buf_qkv, 768, 256);
  attn_row_kernel<<<1024, 256, 0, stream>>>(buf_qkv, buf_bias, buf_o);
  gemm_mfma_kernel<1><<<dim3(256, 2), 256, 0, stream>>>(
      ln_bf, w_rg, row_gate_b, buf_o, g_bf, 256, 256);
  gemm_mfma_kernel<2><<<dim3(256, 2), 256, 0, stream>>>(
      g_bf, w_ro, out_bias, node, buf_node, 256, 256);

  // ---- Phase B: MSAColumnAttention ----
  ln256_bf_kernel<<<32768, 64, 0, stream>>>(buf_node, ln_bf, ln_mc_g, ln_mc_b);
  gemm_mfma_kernel<0><<<dim3(256, 6), 256, 0, stream>>>(
      ln_bf, w_cqkv, col_qkv_b, nullptr, buf_qkv, 768, 256);
  attn_col_kernel<<<2048, 128, 0, stream>>>(buf_qkv, buf_o);
  gemm_mfma_kernel<1><<<dim3(256, 2), 256, 0, stream>>>(
      ln_bf, w_cg, col_gate_b, buf_o, g_bf, 256, 256);
  gemm_mfma_kernel<2><<<dim3(256, 2), 256, 0, stream>>>(
      g_bf, w_co, col_o_b, buf_node, buf_node, 256, 256);

  // ---- Phase C: MSATransition ----
  ln256_bf_kernel<<<32768, 64, 0, stream>>>(buf_node, ln_bf, ln_t_g, ln_t_b);
  gemm_mfma_kernel<3><<<dim3(256, 8), 256, 0, stream>>>(
      ln_bf, w_t1, t_b1, nullptr, h_bf, 1024, 256);
  gemm_mfma_kernel<2><<<dim3(256, 2), 256, 0, stream>>>(
      h_bf, w_t2, t_b2, buf_node, out, 256, 1024);
}

// Round 3
// 449.367 us; speedup vs baseline: 3.2185x; 1.6839x over previous
//
#include <hip/hip_runtime.h>
#include <hip/hip_bf16.h>

#define EPS 1e-5f

typedef __hip_bfloat16 bf16;
typedef __attribute__((ext_vector_type(8))) short short8v;   // 8 bf16 = 4 VGPRs
typedef __attribute__((ext_vector_type(4))) float f32x4;

// ---------------------------------------------------------------------------
// global -> LDS direct copy, 16B per lane
// ---------------------------------------------------------------------------
__device__ inline void load_lds16(const void* g, void* l) {
  __builtin_amdgcn_global_load_lds(
      (const __attribute__((address_space(1))) void*)g,
      (__attribute__((address_space(3))) void*)l, 16, 0, 0);
}

// ---------------------------------------------------------------------------
// f32 -> bf16 elementwise (weights), 4 elems/thread
// ---------------------------------------------------------------------------
__global__ __launch_bounds__(256) void cvt_bf16_kernel(
    const float* __restrict__ in, bf16* __restrict__ out, int n4) {
  int i = blockIdx.x * 256 + threadIdx.x;
  if (i >= n4) return;
  float4 v = reinterpret_cast<const float4*>(in)[i];
  union { ushort4 u; bf16 h[4]; } cv;
  cv.h[0] = __float2bfloat16(v.x);
  cv.h[1] = __float2bfloat16(v.y);
  cv.h[2] = __float2bfloat16(v.z);
  cv.h[3] = __float2bfloat16(v.w);
  reinterpret_cast<ushort4*>(out)[i] = cv.u;
}

// ---------------------------------------------------------------------------
// LayerNorm over last dim = 256 -> bf16 output. One wave per row.
// ---------------------------------------------------------------------------
__global__ __launch_bounds__(64) void ln256_bf_kernel(
    const float* __restrict__ in, bf16* __restrict__ out,
    const float* __restrict__ g, const float* __restrict__ b) {
  int row = blockIdx.x;
  int lane = threadIdx.x;
  float4 x = reinterpret_cast<const float4*>(in + (size_t)row * 256)[lane];
  float s = x.x + x.y + x.z + x.w;
  float sq = x.x * x.x + x.y * x.y + x.z * x.z + x.w * x.w;
#pragma unroll
  for (int off = 32; off >= 1; off >>= 1) {
    s += __shfl_xor(s, off);
    sq += __shfl_xor(sq, off);
  }
  float mean = s * (1.0f / 256.0f);
  float inv = rsqrtf(sq * (1.0f / 256.0f) - mean * mean + EPS);
  float4 gv = reinterpret_cast<const float4*>(g)[lane];
  float4 bv = reinterpret_cast<const float4*>(b)[lane];
  union { ushort4 u; bf16 h[4]; } cv;
  cv.h[0] = __float2bfloat16((x.x - mean) * inv * gv.x + bv.x);
  cv.h[1] = __float2bfloat16((x.y - mean) * inv * gv.y + bv.y);
  cv.h[2] = __float2bfloat16((x.z - mean) * inv * gv.z + bv.z);
  cv.h[3] = __float2bfloat16((x.w - mean) * inv * gv.w + bv.w);
  reinterpret_cast<ushort4*>(out + (size_t)row * 256)[lane] = cv.u;
}

// ---------------------------------------------------------------------------
// Fused pair LayerNorm + bias einsum: bT[h][k][q] (fp32)
// ---------------------------------------------------------------------------
__global__ __launch_bounds__(64) void pair_bias_kernel(
    const float* __restrict__ pair, const float* __restrict__ g,
    const float* __restrict__ b, const float* __restrict__ bw,
    float* __restrict__ bT) {
  int idx = blockIdx.x;  // q*256 + k
  int q = idx >> 8;
  int k = idx & 255;
  int lane = threadIdx.x;
  float2 z = reinterpret_cast<const float2*>(pair + (size_t)idx * 128)[lane];
  float s = z.x + z.y;
  float sq = z.x * z.x + z.y * z.y;
#pragma unroll
  for (int off = 32; off >= 1; off >>= 1) {
    s += __shfl_xor(s, off);
    sq += __shfl_xor(sq, off);
  }
  float mean = s * (1.0f / 128.0f);
  float inv = rsqrtf(sq * (1.0f / 128.0f) - mean * mean + EPS);
  float2 gv = reinterpret_cast<const float2*>(g)[lane];
  float2 bv = reinterpret_cast<const float2*>(b)[lane];
  float z0 = (z.x - mean) * inv * gv.x + bv.x;
  float z1 = (z.y - mean) * inv * gv.y + bv.y;
#pragma unroll
  for (int h = 0; h < 8; ++h) {
    float2 w = reinterpret_cast<const float2*>(bw + h * 128)[lane];
    float p = z0 * w.x + z1 * w.y;
#pragma unroll
    for (int off = 32; off >= 1; off >>= 1) p += __shfl_xor(p, off);
    if (lane == 0) bT[((size_t)h * 256 + k) * 256 + q] = p;
  }
}

// ---------------------------------------------------------------------------
// MFMA GEMM: out[M,N] = A[M,K] @ W[N,K]^T (+bias +epilogue), bf16 in, fp32 acc
// EPI 0: bf16 out = acc + bias                     (qkv)
// EPI 1: bf16 out = aux * sigmoid(acc + bias)      (gate; aux = attn out f32)
// EPI 2: fp32 out = aux + acc + bias               (residual)
// EPI 3: bf16 out = relu(acc + bias)               (transition hidden)
// ---------------------------------------------------------------------------
template <int EPI>
__global__ __launch_bounds__(256) void gemm_mfma_kernel(
    const bf16* __restrict__ A, const bf16* __restrict__ W,
    const float* __restrict__ bias, const float* __restrict__ aux, void* out,
    int N, int K) {
  __shared__ __align__(16) short As[128 * 32];
  __shared__ __align__(16) short Bs[128 * 32];
  int bm = blockIdx.x, bn = blockIdx.y;
  int tid = threadIdx.x;
  int w = tid >> 6, lane = tid & 63;
  int wr = w >> 1, wc = w & 1;
  int c0 = w * 64 + lane;
  int srow = c0 >> 2, skq = c0 & 3;
  const short* Abase = (const short*)(A + (size_t)(bm * 128) * K);
  const short* Wbase = (const short*)(W + (size_t)(bn * 128) * K);
  f32x4 acc[4][4] = {};
  int lrow = lane & 15, kq = lane >> 4;

  for (int k0 = 0; k0 < K; k0 += 32) {
    __syncthreads();
    load_lds16(Abase + (size_t)srow * K + k0 + skq * 8, &As[c0 * 8]);
    load_lds16(Abase + (size_t)(srow + 64) * K + k0 + skq * 8,
               &As[(256 + c0) * 8]);
    load_lds16(Wbase + (size_t)srow * K + k0 + skq * 8, &Bs[c0 * 8]);
    load_lds16(Wbase + (size_t)(srow + 64) * K + k0 + skq * 8,
               &Bs[(256 + c0) * 8]);
    __syncthreads();
    short8v af[4], bfv[4];
#pragma unroll
    for (int i = 0; i < 4; ++i)
      af[i] = *reinterpret_cast<const short8v*>(
          &As[(wr * 64 + i * 16 + lrow) * 32 + kq * 8]);
#pragma unroll
    for (int j = 0; j < 4; ++j)
      bfv[j] = *reinterpret_cast<const short8v*>(
          &Bs[(wc * 64 + j * 16 + lrow) * 32 + kq * 8]);
#pragma unroll
    for (int i = 0; i < 4; ++i)
#pragma unroll
      for (int j = 0; j < 4; ++j)
        acc[i][j] = __builtin_amdgcn_mfma_f32_16x16x32_bf16(af[i], bfv[j],
                                                            acc[i][j], 0, 0, 0);
  }

  float* outF = (float*)out;
  bf16* outB = (bf16*)out;
  int r4 = (lane >> 4) * 4;
#pragma unroll
  for (int j = 0; j < 4; ++j) {
    int c = bn * 128 + wc * 64 + j * 16 + lrow;
    float bv = bias ? bias[c] : 0.0f;
#pragma unroll
    for (int i = 0; i < 4; ++i) {
      int r0 = bm * 128 + wr * 64 + i * 16 + r4;
#pragma unroll
      for (int reg = 0; reg < 4; ++reg) {
        size_t off = (size_t)(r0 + reg) * N + c;
        float v = acc[i][j][reg] + bv;
        if (EPI == 0) {
          outB[off] = __float2bfloat16(v);
        } else if (EPI == 1) {
          float gt = 1.0f / (1.0f + __expf(-v));
          outB[off] = __float2bfloat16(aux[off] * gt);
        } else if (EPI == 2) {
          outF[off] = v + aux[off];
        } else {
          outB[off] = __float2bfloat16(fmaxf(v, 0.0f));
        }
      }
    }
  }
}

// ---------------------------------------------------------------------------
// MFMA flash attention. ROWMODE: block=(s,h), 256 q, 256 kv, pair bias.
//                      !ROWMODE: block=(r,h), 128 q, 128 kv, no bias.
// 4 waves; wave owns QT*16 q-rows. Swapped QK^T (S^T frags), online softmax,
// P via swizzled per-wave LDS, V transposed+swizzled in LDS.
// ---------------------------------------------------------------------------
template <bool ROWMODE>
__global__ __launch_bounds__(256) void attn_mfma_kernel(
    const bf16* __restrict__ qkv, const float* __restrict__ bT,
    float* __restrict__ o) {
  constexpr int KVLEN = ROWMODE ? 256 : 128;
  constexpr int QT = ROWMODE ? 4 : 2;          // q-tiles (16 rows) per wave
  constexpr int KOUT = KVLEN / 64;             // k-chunks of 64
  constexpr int STRIDE = ROWMODE ? 768 : 768 * 256;    // elems between rows
  constexpr int OSTRIDE = ROWMODE ? 256 : 256 * 256;
  __shared__ __align__(16) short K_lds[KVLEN * 32];    // [k][c] swizzled
  __shared__ __align__(16) short Vt_lds[32 * KVLEN];   // [c][k] swizzled
  __shared__ __align__(16) short P_lds[4][QT * 16 * 64];  // per-wave [q][k] swz

  int b = blockIdx.x;
  int idx = b >> 3, h = b & 7;
  const short* qb =
      (const short*)qkv + (size_t)idx * (ROWMODE ? 196608 : 768);
  float* ob = o + (size_t)idx * (ROWMODE ? 65536 : 256);
  int tid = threadIdx.x;
  int w = tid >> 6, lane = tid & 63;
  int l15 = lane & 15, l4 = lane >> 4;

  // ---- stage K via global_load_lds, source pre-swizzled (m173) ----
#pragma unroll
  for (int rnd = 0; rnd < KVLEN / 64; ++rnd) {
    int c = rnd * 256 + tid;  // = uniform + lane*1 -> dest = base + lane*16
    int row = c >> 2;
    int kq = (c & 3) ^ ((row >> 1) & 3);
    load_lds16(qb + (size_t)row * STRIDE + 256 + h * 32 + kq * 8,
               &K_lds[c * 8]);
  }
  // ---- stage V transposed + swizzled (reg-staged, pack k-pairs) ----
#pragma unroll
  for (int it = 0; it < KVLEN / 128; ++it) {
    int tt = it * 256 + tid;
    int kp = tt >> 2;          // k = 2*kp
    int cc = (tt & 3) * 8;
    short8v va = *reinterpret_cast<const short8v*>(
        qb + (size_t)(2 * kp) * STRIDE + 512 + h * 32 + cc);
    short8v vb = *reinterpret_cast<const short8v*>(
        qb + (size_t)(2 * kp + 1) * STRIDE + 512 + h * 32 + cc);
    int k = 2 * kp;
    int u = k >> 3;
    int klo = k & 7;
#pragma unroll
    for (int e = 0; e < 8; ++e) {
      int cI = cc + e;
      int up = u ^ (cI & 7);
      unsigned pk =
          (unsigned)(unsigned short)va[e] | ((unsigned)(unsigned short)vb[e] << 16);
      *reinterpret_cast<unsigned*>(&Vt_lds[cI * KVLEN + up * 8 + klo]) = pk;
    }
  }
  __syncthreads();

  // ---- Q fragments (B-operand): lane = q row l15, c-chunk l4*8 ----
  int q0 = w * QT * 16;
  short8v qf[QT];
#pragma unroll
  for (int j = 0; j < QT; ++j)
    qf[j] = *reinterpret_cast<const short8v*>(
        qb + (size_t)(q0 + j * 16 + l15) * STRIDE + h * 32 + l4 * 8);

  float mrun[QT], lrun[QT];
#pragma unroll
  for (int j = 0; j < QT; ++j) { mrun[j] = -3.0e38f; lrun[j] = 0.0f; }
  f32x4 acc_o[QT][2] = {};

  const float SC = 0.17677669529663687f;  // 32^-0.5
  const float L2E = 1.4426950408889634f;
  const f32x4 zf = {0.f, 0.f, 0.f, 0.f};

#pragma unroll 1
  for (int kt = 0; kt < KOUT; ++kt) {
    // ---- QK^T chunk: S^T [64k][QT*16 q] ----
    f32x4 accs[4][QT];
#pragma unroll
    for (int i = 0; i < 4; ++i) {
      int krow = kt * 64 + i * 16 + l15;
      short8v kf = *reinterpret_cast<const short8v*>(
          &K_lds[krow * 32 + ((l4 ^ ((krow >> 1) & 3)) * 8)]);
#pragma unroll
      for (int j = 0; j < QT; ++j)
        accs[i][j] =
            __builtin_amdgcn_mfma_f32_16x16x32_bf16(kf, qf[j], zf, 0, 0, 0);
    }
    // ---- logits = S*scale (+ bias) ----
#pragma unroll
    for (int i = 0; i < 4; ++i)
#pragma unroll
      for (int j = 0; j < QT; ++j) {
#pragma unroll
        for (int r = 0; r < 4; ++r) {
          float v = accs[i][j][r] * SC;
          if (ROWMODE) {
            int kg = kt * 64 + i * 16 + l4 * 4 + r;
            int qg = q0 + j * 16 + l15;
            v += bT[(size_t)h * 65536 + (size_t)kg * 256 + qg];
          }
          accs[i][j][r] = v;
        }
      }
    // ---- online softmax per q-tile ----
#pragma unroll
    for (int j = 0; j < QT; ++j) {
      float mx = -3.0e38f;
#pragma unroll
      for (int i = 0; i < 4; ++i)
#pragma unroll
        for (int r = 0; r < 4; ++r) mx = fmaxf(mx, accs[i][j][r]);
      mx = fmaxf(mx, __shfl_xor(mx, 16));
      mx = fmaxf(mx, __shfl_xor(mx, 32));
      float mnew = fmaxf(mrun[j], mx);
      float corr = exp2f((mrun[j] - mnew) * L2E);
      mrun[j] = mnew;
      float sum = 0.0f;
#pragma unroll
      for (int i = 0; i < 4; ++i)
#pragma unroll
        for (int r = 0; r < 4; ++r) {
          float p = exp2f((accs[i][j][r] - mnew) * L2E);
          accs[i][j][r] = p;
          sum += p;
        }
      sum += __shfl_xor(sum, 16);
      sum += __shfl_xor(sum, 32);
      lrun[j] = lrun[j] * corr + sum;
      // rescale O accumulator (corr broadcast to D-layout rows)
#pragma unroll
      for (int r = 0; r < 4; ++r) {
        float cr = __shfl(corr, l4 * 4 + r);
        acc_o[j][0][r] *= cr;
        acc_o[j][1][r] *= cr;
      }
      // pack P -> per-wave LDS [q][k], swizzled
      int q = j * 16 + l15;
      int qs = q & 7;
#pragma unroll
      for (int i = 0; i < 4; ++i) {
        union { short4 s4; bf16 h4[4]; } pk;
#pragma unroll
        for (int r = 0; r < 4; ++r) pk.h4[r] = __float2bfloat16(accs[i][j][r]);
        int unit = i * 2 + (l4 >> 1);
        int off = (l4 & 1) * 4;
        *reinterpret_cast<short4*>(
            &P_lds[w][q * 64 + (unit ^ qs) * 8 + off]) = pk.s4;
      }
    }
    // ---- PV: acc_o += P @ V ----
#pragma unroll
    for (int ks = 0; ks < 2; ++ks) {
      short8v vf[2];
#pragma unroll
      for (int ct = 0; ct < 2; ++ct) {
        int c = ct * 16 + l15;
        int u = kt * 8 + ks * 4 + l4;
        vf[ct] = *reinterpret_cast<const short8v*>(
            &Vt_lds[c * KVLEN + (u ^ (c & 7)) * 8]);
      }
#pragma unroll
      for (int j = 0; j < QT; ++j) {
        int q = j * 16 + l15;
        short8v pf = *reinterpret_cast<const short8v*>(
            &P_lds[w][q * 64 + ((ks * 4 + l4) ^ (q & 7)) * 8]);
#pragma unroll
        for (int ct = 0; ct < 2; ++ct)
          acc_o[j][ct] = __builtin_amdgcn_mfma_f32_16x16x32_bf16(
              pf, vf[ct], acc_o[j][ct], 0, 0, 0);
      }
    }
  }

  // ---- epilogue: normalize by 1/l and store f32 ----
#pragma unroll
  for (int j = 0; j < QT; ++j) {
    float inv = 1.0f / lrun[j];
#pragma unroll
    for (int r = 0; r < 4; ++r) {
      float rv = __shfl(inv, l4 * 4 + r);
      int row = q0 + j * 16 + l4 * 4 + r;
      float* op = ob + (size_t)row * OSTRIDE + h * 32 + l15;
      op[0] = acc_o[j][0][r] * rv;
      op[16] = acc_o[j][1][r] * rv;
    }
  }
}

// ---------------------------------------------------------------------------
extern "C" void kernel_launch(void* const* d_in, const int* in_sizes, int n_in,
                              void* d_out, int out_size, void* d_ws,
                              size_t ws_size, hipStream_t stream) {
  (void)in_sizes; (void)n_in; (void)out_size; (void)ws_size;
  const float* node      = (const float*)d_in[0];
  const float* pair      = (const float*)d_in[1];
  const float* ln_mr_g   = (const float*)d_in[2];
  const float* ln_mr_b   = (const float*)d_in[3];
  const float* ln_z_g    = (const float*)d_in[4];
  const float* ln_z_b    = (const float*)d_in[5];
  const float* b_weights = (const float*)d_in[6];
  const float* row_qkv_w = (const float*)d_in[7];
  const float* row_qkv_b = (const float*)d_in[8];
  const float* row_gate_w= (const float*)d_in[9];
  const float* row_gate_b= (const float*)d_in[10];
  const float* row_o_w   = (const float*)d_in[11];
  const float* out_bias  = (const float*)d_in[12];
  const float* ln_mc_g   = (const float*)d_in[13];
  const float* ln_mc_b   = (const float*)d_in[14];
  const float* col_qkv_w = (const float*)d_in[15];
  const float* col_qkv_b = (const float*)d_in[16];
  const float* col_gate_w= (const float*)d_in[17];
  const float* col_gate_b= (const float*)d_in[18];
  const float* col_o_w   = (const float*)d_in[19];
  const float* col_o_b   = (const float*)d_in[20];
  const float* ln_t_g    = (const float*)d_in[21];
  const float* ln_t_b    = (const float*)d_in[22];
  const float* t_w1      = (const float*)d_in[23];
  const float* t_b1      = (const float*)d_in[24];
  const float* t_w2      = (const float*)d_in[25];
  const float* t_b2      = (const float*)d_in[26];
  float* out = (float*)d_out;

  const size_t NR = 32768;
  char* p = (char*)d_ws;
  float* buf_node = (float*)p; p += NR * 256 * 4;
  char*  qkv_region = p;       p += NR * 768 * 4;
  float* buf_o    = (float*)p; p += NR * 256 * 4;
  float* buf_bias = (float*)p; p += 8 * 256 * 256 * 4;
  bf16* ln_bf     = (bf16*)p;  p += NR * 256 * 2;
  bf16* g_bf      = (bf16*)p;  p += NR * 256 * 2;
  bf16* qkv_bf = (bf16*)qkv_region;   // [32768][768] bf16
  bf16* h_bf   = (bf16*)qkv_region;   // phase C: [32768][1024] bf16
  bf16* w_rqkv = (bf16*)p; p += 768 * 256 * 2;
  bf16* w_rg   = (bf16*)p; p += 256 * 256 * 2;
  bf16* w_ro   = (bf16*)p; p += 256 * 256 * 2;
  bf16* w_cqkv = (bf16*)p; p += 768 * 256 * 2;
  bf16* w_cg   = (bf16*)p; p += 256 * 256 * 2;
  bf16* w_co   = (bf16*)p; p += 256 * 256 * 2;
  bf16* w_t1   = (bf16*)p; p += 1024 * 256 * 2;
  bf16* w_t2   = (bf16*)p; p += 256 * 1024 * 2;

  // ---- weight conversions (fp32 -> bf16) ----
  cvt_bf16_kernel<<<192, 256, 0, stream>>>(row_qkv_w, w_rqkv, 49152);
  cvt_bf16_kernel<<<64, 256, 0, stream>>>(row_gate_w, w_rg, 16384);
  cvt_bf16_kernel<<<64, 256, 0, stream>>>(row_o_w, w_ro, 16384);
  cvt_bf16_kernel<<<192, 256, 0, stream>>>(col_qkv_w, w_cqkv, 49152);
  cvt_bf16_kernel<<<64, 256, 0, stream>>>(col_gate_w, w_cg, 16384);
  cvt_bf16_kernel<<<64, 256, 0, stream>>>(col_o_w, w_co, 16384);
  cvt_bf16_kernel<<<256, 256, 0, stream>>>(t_w1, w_t1, 65536);
  cvt_bf16_kernel<<<256, 256, 0, stream>>>(t_w2, w_t2, 65536);

  // ---- Phase A: MSARowAttentionWithPairBias ----
  ln256_bf_kernel<<<32768, 64, 0, stream>>>(node, ln_bf, ln_mr_g, ln_mr_b);
  pair_bias_kernel<<<65536, 64, 0, stream>>>(pair, ln_z_g, ln_z_b, b_weights,
                                             buf_bias);
  gemm_mfma_kernel<0><<<dim3(256, 6), 256, 0, stream>>>(
      ln_bf, w_rqkv, row_qkv_b, nullptr, qkv_bf, 768, 256);
  attn_mfma_kernel<true><<<1024, 256, 0, stream>>>(qkv_bf, buf_bias, buf_o);
  gemm_mfma_kernel<1><<<dim3(256, 2), 256, 0, stream>>>(
      ln_bf, w_rg, row_gate_b, buf_o, g_bf, 256, 256);
  gemm_mfma_kernel<2><<<dim3(256, 2), 256, 0, stream>>>(
      g_bf, w_ro, out_bias, node, buf_node, 256, 256);

  // ---- Phase B: MSAColumnAttention ----
  ln256_bf_kernel<<<32768, 64, 0, stream>>>(buf_node, ln_bf, ln_mc_g, ln_mc_b);
  gemm_mfma_kernel<0><<<dim3(256, 6), 256, 0, stream>>>(
      ln_bf, w_cqkv, col_qkv_b, nullptr, qkv_bf, 768, 256);
  attn_mfma_kernel<false><<<2048, 256, 0, stream>>>(qkv_bf, nullptr, buf_o);
  gemm_mfma_kernel<1><<<dim3(256, 2), 256, 0, stream>>>(
      ln_bf, w_cg, col_gate_b, buf_o, g_bf, 256, 256);
  gemm_mfma_kernel<2><<<dim3(256, 2), 256, 0, stream>>>(
      g_bf, w_co, col_o_b, buf_node, buf_node, 256, 256);

  // ---- Phase C: MSATransition ----
  ln256_bf_kernel<<<32768, 64, 0, stream>>>(buf_node, ln_bf, ln_t_g, ln_t_b);
  gemm_mfma_kernel<3><<<dim3(256, 8), 256, 0, stream>>>(
      ln_bf, w_t1, t_b1, nullptr, h_bf, 1024, 256);
  gemm_mfma_kernel<2><<<dim3(256, 2), 256, 0, stream>>>(
      h_bf, w_t2, t_b2, buf_node, out, 256, 1024);
}